// Round 2
// 306.148 us; speedup vs baseline: 1.2788x; 1.2788x over previous
//
#include <hip/hip_runtime.h>

#define CMID 32
#define CIN 128
#define HNB 32
#define KP 15
#define NEG 0.1f
#define EPS 1e-5f

// ---------------------------------------------------------------------------
// K1: y1 = s_feats @ w_u1  (M x 128 @ 128 x 32), plus per-channel sum/sumsq
// stats (for BN over the M axis) via block partials + atomics.
// ---------------------------------------------------------------------------
__global__ __launch_bounds__(256) void k1_gemm1(
    const float* __restrict__ A,   // s_feats (M,128)
    const float* __restrict__ B,   // w_u1 (128,32)
    float* __restrict__ y1,        // (M,32)
    float* __restrict__ st,        // stats: [0:32) sum, [32:64) sumsq
    int M)
{
    __shared__ float Bs[CIN * CMID];   // 16 KB
    __shared__ float As[32 * CIN];     // 16 KB
    __shared__ float red[256];
    int t = threadIdx.x;
    for (int i = t; i < CIN * CMID; i += 256) Bs[i] = B[i];
    int m0 = blockIdx.x * 32;
    int rows = min(32, M - m0);
    for (int i = t; i < rows * CIN; i += 256) As[i] = A[(size_t)m0 * CIN + i];
    __syncthreads();

    float sum = 0.f, sq = 0.f;
    int c = t & 31;
#pragma unroll
    for (int i = 0; i < 4; ++i) {
        int p = t + i * 256;
        int r = p >> 5;             // channel = p & 31 == c (256 % 32 == 0)
        if (r < rows) {
            float acc = 0.f;
#pragma unroll 8
            for (int j = 0; j < CIN; ++j) acc += As[r * CIN + j] * Bs[j * CMID + c];
            y1[(size_t)(m0 + r) * CMID + c] = acc;
            sum += acc; sq += acc * acc;
        }
    }
    red[t] = sum; __syncthreads();
    if (t < 32) { float s = 0.f; for (int i = 0; i < 8; ++i) s += red[t + 32 * i]; atomicAdd(&st[t], s); }
    __syncthreads();
    red[t] = sq; __syncthreads();
    if (t < 32) { float s = 0.f; for (int i = 0; i < 8; ++i) s += red[t + 32 * i]; atomicAdd(&st[32 + t], s); }
}

// ---------------------------------------------------------------------------
// K3: KPInv conv, v2 "role-switching" layout.
// One wave handles TWO points (p = lane>>5 selects the point, q = lane&31).
// Phases alternate the meaning of q between "neighbor h" and "channel c",
// exchanging data through per-wave LDS slices (intra-wave lockstep + in-order
// DS => no __syncthreads; wave_barrier() pins compiler ordering).
//
//   P1 (q=h): gather y1 row of neighbor h, BN+lrelu, store TRANSPOSED into
//             vbuf[c][h] (stride-32 rows, 4-float chunks XOR-swizzled by c&7
//             so the b128 row reads later hit the bank floor). Compute
//             infl[k] once per (m,h), keep in registers.
//   P2 (q=c): center[c] = max over h (8 x ds_read_b128 + in-reg max);
//             MLP1: h1[c&7] = lrelu(center . wg1[:,c&7] + bg1[c&7]);
//             MLP2: w[c] = h1 . wg2[:,c] + bg2[c] for c<30 (w[k*2+g] order).
//   P3 (q=h): s_g[h] = sum_k infl[k] * w[2k+g], g=0,1 -> LDS s[g][h]
//   P4 (q=c): out[c] = sum_h vbuf[c][h] * s[c>>4][h], store x2.
//
// ~250 VALU + ~40 DS wave-insts per point vs ~820 VALU + ~170 DS for the
// butterfly version (MLP no longer replicated across 32 h-lanes; both
// h-reductions serial in-register). LDS/block ~39.9 KB -> 4 blocks/CU.
// ---------------------------------------------------------------------------
__global__ __launch_bounds__(256, 4) void k3_kpinv(
    const float* __restrict__ y1, const float* __restrict__ st,
    const float* __restrict__ q_pts, const float* __restrict__ s_pts,
    const int* __restrict__ idx, const float* __restrict__ kp,
    const float* __restrict__ g_u1, const float* __restrict__ b_u1,
    const float* __restrict__ w_g1, const float* __restrict__ b_g1,
    const float* __restrict__ w_g2, const float* __restrict__ b_g2,
    float* __restrict__ x2, int M)
{
    __shared__ __align__(16) float a1s[32], b1s[32];
    __shared__ __align__(16) float wg1[32 * 8];
    __shared__ __align__(16) float bg1[8];
    __shared__ __align__(16) float wg2[8 * 30];
    __shared__ __align__(16) float bg2[32];              // padded 30->32
    __shared__ __align__(16) float kps[KP * 3 + 1];
    __shared__ __align__(16) float vbuf[4][2][32 * 32];  // [wave][p][c*32 + swz(h)]
    __shared__ __align__(16) float aux[4][2][144];       // center[0:32) h1[32:40) w[40:72) s[72:136)

    int t = threadIdx.x;
    if (t < 32) {
        float mean = st[t] * (1.0f / M);
        float var  = st[32 + t] * (1.0f / M) - mean * mean;
        float inv  = rsqrtf(var + EPS);
        float a = g_u1[t] * inv;
        a1s[t] = a;
        b1s[t] = b_u1[t] - mean * a;
    }
    wg1[t & 255] = w_g1[t & 255];          // 256 threads, 256 elems
    if (t < 8)   bg1[t] = b_g1[t];
    if (t < 240) wg2[t] = w_g2[t];
    if (t < 30)  bg2[t] = b_g2[t];
    else if (t < 32) bg2[t] = 0.f;
    if (t < KP * 3) kps[t] = kp[t];
    __syncthreads();

    int wave = t >> 6, lane = t & 63;
    int p = lane >> 5;          // which of the wave's two points
    int q = lane & 31;          // h in phases 1/3, c in phases 2/4
    int m = blockIdx.x * 8 + wave * 2 + p;
    bool valid = (m < M);
    int mm = valid ? m : 0;
    float* vb = &vbuf[wave][p][0];
    float* ax = &aux[wave][p][0];

    // ---------------- Phase 1: q = h ----------------
    int h = q;
    int n = idx[(size_t)mm * HNB + h];
    float qx = q_pts[mm * 3 + 0], qy = q_pts[mm * 3 + 1], qz = q_pts[mm * 3 + 2];
    float dx = s_pts[n * 3 + 0] - qx;
    float dy = s_pts[n * 3 + 1] - qy;
    float dz = s_pts[n * 3 + 2] - qz;

    float infl[KP];
#pragma unroll
    for (int k = 0; k < KP; ++k) {
        float ex = dx - kps[k * 3 + 0];
        float ey = dy - kps[k * 3 + 1];
        float ez = dz - kps[k * 3 + 2];
        float d = sqrtf(ex * ex + ey * ey + ez * ez);
        infl[k] = fmaxf(1.0f - d, 0.f);
    }

    // gather + BN + lrelu, transposed swizzled store:
    // logical v[c][h] lives at vb[c*32 + 4*((h>>2) ^ (c&7)) + (h&3)]
    {
        const float4* row = (const float4*)(y1 + (size_t)n * CMID);
        int hq4 = h >> 2, h3 = h & 3;
#pragma unroll
        for (int jj = 0; jj < 8; ++jj) {
            float4 f = row[jj];
            float vv[4] = {f.x, f.y, f.z, f.w};
#pragma unroll
            for (int e = 0; e < 4; ++e) {
                int c = jj * 4 + e;
                float x = vv[e] * a1s[c] + b1s[c];
                x = fmaxf(x, NEG * x);
                vb[(c << 5) + ((hq4 ^ (c & 7)) << 2) + h3] = x;
            }
        }
    }
    __builtin_amdgcn_wave_barrier();

    // ---------------- Phase 2: q = c ----------------
    {
        int c = q;
        int c7 = c & 7;
        const float* vrow = vb + (c << 5);
        float cm = -1e30f;
#pragma unroll
        for (int j = 0; j < 8; ++j) {
            const float4 f = *(const float4*)(vrow + ((j ^ c7) << 2));
            cm = fmaxf(fmaxf(fmaxf(cm, f.x), fmaxf(f.y, f.z)), f.w);
        }
        ax[c] = cm;                       // center[c]
        __builtin_amdgcn_wave_barrier();

        // MLP1: each lane computes h1[c&7] (4 redundant copies per point)
        int jm = c & 7;
        float acc = bg1[jm];
#pragma unroll
        for (int cc = 0; cc < 8; ++cc) {
            const float4 ce = *(const float4*)(ax + (cc << 2));
            acc += ce.x * wg1[(cc * 4 + 0) * 8 + jm];
            acc += ce.y * wg1[(cc * 4 + 1) * 8 + jm];
            acc += ce.z * wg1[(cc * 4 + 2) * 8 + jm];
            acc += ce.w * wg1[(cc * 4 + 3) * 8 + jm];
        }
        float h1v = fmaxf(acc, NEG * acc);
        if (c < 8) ax[32 + c] = h1v;
        __builtin_amdgcn_wave_barrier();

        // MLP2: w_flat[c] = h1 . wg2[:,c] + bg2[c]   (c = k*2+g, c<30)
        float wv = 0.f;
        if (c < 30) {
            const float4 ha = *(const float4*)(ax + 32);
            const float4 hb = *(const float4*)(ax + 36);
            wv = bg2[c]
               + ha.x * wg2[0 * 30 + c] + ha.y * wg2[1 * 30 + c]
               + ha.z * wg2[2 * 30 + c] + ha.w * wg2[3 * 30 + c]
               + hb.x * wg2[4 * 30 + c] + hb.y * wg2[5 * 30 + c]
               + hb.z * wg2[6 * 30 + c] + hb.w * wg2[7 * 30 + c];
        }
        ax[40 + c] = wv;
    }
    __builtin_amdgcn_wave_barrier();

    // ---------------- Phase 3: q = h ----------------
    {
        float wf[32];
#pragma unroll
        for (int j = 0; j < 8; ++j) {
            const float4 wc = *(const float4*)(ax + 40 + (j << 2));
            wf[j * 4 + 0] = wc.x; wf[j * 4 + 1] = wc.y;
            wf[j * 4 + 2] = wc.z; wf[j * 4 + 3] = wc.w;
        }
        float s0 = 0.f, s1 = 0.f;
#pragma unroll
        for (int k = 0; k < KP; ++k) {
            s0 += infl[k] * wf[2 * k + 0];
            s1 += infl[k] * wf[2 * k + 1];
        }
        ax[72 + q]  = s0;    // s[g=0][h]
        ax[104 + q] = s1;    // s[g=1][h]
    }
    __builtin_amdgcn_wave_barrier();

    // ---------------- Phase 4: q = c ----------------
    {
        int c = q;
        int c7 = c & 7;
        const float* sbuf = ax + 72 + ((c >> 4) << 5);
        const float* vrow = vb + (c << 5);
        float o = 0.f;
#pragma unroll
        for (int j = 0; j < 8; ++j) {
            // physical chunk (j^c7) of row c holds logical h-chunk j
            const float4 vv = *(const float4*)(vrow + ((j ^ c7) << 2));
            const float4 ss = *(const float4*)(sbuf + (j << 2));
            o += vv.x * ss.x + vv.y * ss.y + vv.z * ss.z + vv.w * ss.w;
        }
        if (valid) x2[(size_t)m * CMID + c] = o;
    }
}

// ---------------------------------------------------------------------------
// K4: per-channel sum/sumsq over x2 (32 channels) -> st[64:96), st[96:128)
// ---------------------------------------------------------------------------
__global__ __launch_bounds__(256) void k4_stats32(
    const float* __restrict__ x2, float* __restrict__ st, int M)
{
    int t = threadIdx.x;
    int c = t & 31;
    float sum = 0.f, sq = 0.f;
    for (int r = blockIdx.x * 8 + (t >> 5); r < M; r += gridDim.x * 8) {
        float v = x2[(size_t)r * CMID + c];
        sum += v; sq += v * v;
    }
    __shared__ float red[256];
    red[t] = sum; __syncthreads();
    if (t < 32) { float s = 0.f; for (int i = 0; i < 8; ++i) s += red[t + 32 * i]; atomicAdd(&st[64 + t], s); }
    __syncthreads();
    red[t] = sq; __syncthreads();
    if (t < 32) { float s = 0.f; for (int i = 0; i < 8; ++i) s += red[t + 32 * i]; atomicAdd(&st[96 + t], s); }
}

// ---------------------------------------------------------------------------
// K6: z = lrelu(bn_c(x2)) @ w_u2 computed on the fly, only stats kept:
// per-channel (128) sum/sumsq -> st[128:256), st[256:384).
// ---------------------------------------------------------------------------
__global__ __launch_bounds__(256) void k6_zstats(
    const float* __restrict__ x2, const float* __restrict__ w_u2,
    const float* __restrict__ g_c, const float* __restrict__ b_c,
    float* __restrict__ st, int M)
{
    __shared__ float Ws[CMID * CIN];   // 16 KB
    __shared__ float S[32 * CMID];     // 4 KB activated rows
    __shared__ float ac[32], bc[32];
    __shared__ float red[256];
    int t = threadIdx.x;
    for (int i = t; i < CMID * CIN; i += 256) Ws[i] = w_u2[i];
    if (t < 32) {
        float mean = st[64 + t] * (1.0f / M);
        float var  = st[96 + t] * (1.0f / M) - mean * mean;
        float inv  = rsqrtf(var + EPS);
        float a = g_c[t] * inv;
        ac[t] = a; bc[t] = b_c[t] - mean * a;
    }
    int m0 = blockIdx.x * 32;
    int rows = min(32, M - m0);
    __syncthreads();
    for (int i = t; i < rows * CMID; i += 256) {
        int c = i & 31;
        float x = x2[(size_t)m0 * CMID + i] * ac[c] + bc[c];
        S[i] = x >= 0.f ? x : NEG * x;
    }
    __syncthreads();
    int o = t & 127, r0 = t >> 7;
    float sum = 0.f, sq = 0.f;
    for (int r = r0; r < rows; r += 2) {
        float acc = 0.f;
#pragma unroll
        for (int j = 0; j < CMID; ++j) acc += S[r * CMID + j] * Ws[j * CIN + o];
        sum += acc; sq += acc * acc;
    }
    red[t] = sum; __syncthreads();
    if (t < 128) atomicAdd(&st[128 + t], red[t] + red[t + 128]);
    __syncthreads();
    red[t] = sq; __syncthreads();
    if (t < 128) atomicAdd(&st[256 + t], red[t] + red[t + 128]);
}

// ---------------------------------------------------------------------------
// K8: recompute z, apply bn_u2, add residual s_feats, lrelu -> out (M,128)
// ---------------------------------------------------------------------------
__global__ __launch_bounds__(256) void k8_final(
    const float* __restrict__ x2, const float* __restrict__ w_u2,
    const float* __restrict__ g_c, const float* __restrict__ b_c,
    const float* __restrict__ g_u2, const float* __restrict__ b_u2,
    const float* __restrict__ s_feats, const float* __restrict__ st,
    float* __restrict__ out, int M)
{
    __shared__ float Ws[CMID * CIN];
    __shared__ float S[32 * CMID];
    __shared__ float ac[32], bc[32];
    __shared__ float a2[128], b2[128];
    int t = threadIdx.x;
    for (int i = t; i < CMID * CIN; i += 256) Ws[i] = w_u2[i];
    if (t < 32) {
        float mean = st[64 + t] * (1.0f / M);
        float var  = st[96 + t] * (1.0f / M) - mean * mean;
        float inv  = rsqrtf(var + EPS);
        float a = g_c[t] * inv;
        ac[t] = a; bc[t] = b_c[t] - mean * a;
    }
    if (t < 128) {
        float mean = st[128 + t] * (1.0f / M);
        float var  = st[256 + t] * (1.0f / M) - mean * mean;
        float inv  = rsqrtf(var + EPS);
        float a = g_u2[t] * inv;
        a2[t] = a; b2[t] = b_u2[t] - mean * a;
    }
    int m0 = blockIdx.x * 32;
    int rows = min(32, M - m0);
    __syncthreads();
    for (int i = t; i < rows * CMID; i += 256) {
        int c = i & 31;
        float x = x2[(size_t)m0 * CMID + i] * ac[c] + bc[c];
        S[i] = x >= 0.f ? x : NEG * x;
    }
    __syncthreads();
    int o = t & 127, r0 = t >> 7;
    for (int r = r0; r < rows; r += 2) {
        float acc = 0.f;
#pragma unroll
        for (int j = 0; j < CMID; ++j) acc += S[r * CMID + j] * Ws[j * CIN + o];
        size_t gi = (size_t)(m0 + r) * CIN + o;
        float val = acc * a2[o] + b2[o] + s_feats[gi];
        out[gi] = val >= 0.f ? val : NEG * val;
    }
}

extern "C" void kernel_launch(void* const* d_in, const int* in_sizes, int n_in,
                              void* d_out, int out_size, void* d_ws, size_t ws_size,
                              hipStream_t stream) {
    const float* q_pts   = (const float*)d_in[0];
    const float* s_pts   = (const float*)d_in[1];
    const float* s_feats = (const float*)d_in[2];
    const int*   idx     = (const int*)d_in[3];
    const float* kp      = (const float*)d_in[4];
    const float* w_u1    = (const float*)d_in[5];
    const float* g_u1    = (const float*)d_in[6];
    const float* b_u1    = (const float*)d_in[7];
    const float* w_g1    = (const float*)d_in[8];
    const float* b_g1    = (const float*)d_in[9];
    const float* w_g2    = (const float*)d_in[10];
    const float* b_g2    = (const float*)d_in[11];
    const float* g_c     = (const float*)d_in[12];
    const float* b_c     = (const float*)d_in[13];
    const float* w_u2    = (const float*)d_in[14];
    const float* g_u2    = (const float*)d_in[15];
    const float* b_u2    = (const float*)d_in[16];

    int M = in_sizes[3] / HNB;   // 50000

    float* ws = (float*)d_ws;
    float* y1 = ws;                       // M*32
    float* x2 = ws + (size_t)M * CMID;    // M*32
    float* st = ws + (size_t)M * 2 * CMID; // 384 floats of stats

    hipMemsetAsync(st, 0, 384 * sizeof(float), stream);

    int nb = (M + 31) / 32;
    k1_gemm1<<<nb, 256, 0, stream>>>(s_feats, w_u1, y1, st, M);
    k3_kpinv<<<(M + 7) / 8, 256, 0, stream>>>(y1, st, q_pts, s_pts, idx, kp,
                                              g_u1, b_u1, w_g1, b_g1, w_g2, b_g2,
                                              x2, M);
    k4_stats32<<<128, 256, 0, stream>>>(x2, st, M);
    k6_zstats<<<nb, 256, 0, stream>>>(x2, w_u2, g_c, b_c, st, M);
    k8_final<<<nb, 256, 0, stream>>>(x2, w_u2, g_c, b_c, g_u2, b_u2,
                                     s_feats, st, (float*)d_out, M);
}

// Round 6
// 253.022 us; speedup vs baseline: 1.5473x; 1.2100x over previous
//
#include <hip/hip_runtime.h>

#define CMID 32
#define CIN 128
#define HNB 32
#define KP 15
#define NEG 0.1f
#define EPS 1e-5f

// ---------------------------------------------------------------------------
// K1: y1 = s_feats @ w_u1  (M x 128 @ 128 x 32) + per-channel sum/sumsq stats.
// Register-tiled: 128-row blocks, thread = (ty,tx) = 4 rows x 4 cols.
// A staged TRANSPOSED in K-chunks of 32 (AsT[j][row]) so the per-j A fragment
// is one ds_read_b128 (8-lane broadcast, conflict-free). 2 DS per 16 FMA.
// ---------------------------------------------------------------------------
__global__ __launch_bounds__(256) void k1_gemm1(
    const float* __restrict__ A,   // s_feats (M,128)
    const float* __restrict__ B,   // w_u1 (128,32)
    float* __restrict__ y1,        // (M,32)
    float* __restrict__ st,        // stats: [0:32) sum, [32:64) sumsq
    int M)
{
    __shared__ __align__(16) float AsT[32 * 128];  // [j_local][row] 16 KB
    __shared__ __align__(16) float Bs[128 * 32];   // 16 KB
    __shared__ __align__(16) float red[256];
    int t = threadIdx.x;
    for (int i = t; i < 128 * 32; i += 256) Bs[i] = B[i];

    int m0 = blockIdx.x * 128;
    int tx = t & 7, ty = t >> 3;        // c0 = 4*tx, r0 = 4*ty
    int srow = t & 127, shh = t >> 7;   // staging: row, col-half
    float acc[4][4] = {{0.f}};

    for (int ch = 0; ch < 4; ++ch) {
        __syncthreads();
        // stage chunk: AsT[c_local][row] = A[m0+row][ch*32 + c_local]
        int gr = m0 + srow;
        const float4* ap = (const float4*)(A + (size_t)gr * CIN + ch * 32 + shh * 16);
        float4 f0, f1, f2, f3;
        if (gr < M) { f0 = ap[0]; f1 = ap[1]; f2 = ap[2]; f3 = ap[3]; }
        else { f0 = f1 = f2 = f3 = make_float4(0.f, 0.f, 0.f, 0.f); }
        {
            int cb = shh * 16;
            AsT[(cb + 0) * 128 + srow] = f0.x;  AsT[(cb + 1) * 128 + srow] = f0.y;
            AsT[(cb + 2) * 128 + srow] = f0.z;  AsT[(cb + 3) * 128 + srow] = f0.w;
            AsT[(cb + 4) * 128 + srow] = f1.x;  AsT[(cb + 5) * 128 + srow] = f1.y;
            AsT[(cb + 6) * 128 + srow] = f1.z;  AsT[(cb + 7) * 128 + srow] = f1.w;
            AsT[(cb + 8) * 128 + srow] = f2.x;  AsT[(cb + 9) * 128 + srow] = f2.y;
            AsT[(cb + 10) * 128 + srow] = f2.z; AsT[(cb + 11) * 128 + srow] = f2.w;
            AsT[(cb + 12) * 128 + srow] = f3.x; AsT[(cb + 13) * 128 + srow] = f3.y;
            AsT[(cb + 14) * 128 + srow] = f3.z; AsT[(cb + 15) * 128 + srow] = f3.w;
        }
        __syncthreads();
        const float* bsp = Bs + (ch * 32) * 32 + tx * 4;
#pragma unroll
        for (int jl = 0; jl < 32; ++jl) {
            float4 av = *(const float4*)(AsT + jl * 128 + ty * 4);
            float4 bv = *(const float4*)(bsp + jl * 32);
            acc[0][0] += av.x * bv.x; acc[0][1] += av.x * bv.y; acc[0][2] += av.x * bv.z; acc[0][3] += av.x * bv.w;
            acc[1][0] += av.y * bv.x; acc[1][1] += av.y * bv.y; acc[1][2] += av.y * bv.z; acc[1][3] += av.y * bv.w;
            acc[2][0] += av.z * bv.x; acc[2][1] += av.z * bv.y; acc[2][2] += av.z * bv.z; acc[2][3] += av.z * bv.w;
            acc[3][0] += av.w * bv.x; acc[3][1] += av.w * bv.y; acc[3][2] += av.w * bv.z; acc[3][3] += av.w * bv.w;
        }
    }
    // write y1 (coalesced b128)
#pragma unroll
    for (int i = 0; i < 4; ++i) {
        int r = m0 + ty * 4 + i;
        if (r < M)
            *(float4*)(y1 + (size_t)r * CMID + tx * 4) =
                make_float4(acc[i][0], acc[i][1], acc[i][2], acc[i][3]);
    }
    // stats: per-col sum/sumsq (pad rows contribute 0)
    float s4[4], q4[4];
#pragma unroll
    for (int e = 0; e < 4; ++e) {
        s4[e] = acc[0][e] + acc[1][e] + acc[2][e] + acc[3][e];
        q4[e] = acc[0][e] * acc[0][e] + acc[1][e] * acc[1][e]
              + acc[2][e] * acc[2][e] + acc[3][e] * acc[3][e];
    }
#pragma unroll
    for (int off = 8; off <= 32; off <<= 1) {
#pragma unroll
        for (int e = 0; e < 4; ++e) {
            s4[e] += __shfl_xor(s4[e], off);
            q4[e] += __shfl_xor(q4[e], off);
        }
    }
    int lw = t >> 6, ll = t & 63;
    if (ll < 8) {
#pragma unroll
        for (int e = 0; e < 4; ++e) {
            red[(lw * 8 + ll) * 8 + e] = s4[e];
            red[(lw * 8 + ll) * 8 + 4 + e] = q4[e];
        }
    }
    __syncthreads();
    if (t < 64) {
        int tx2 = t >> 3, k = t & 7;
        float v = red[(0 * 8 + tx2) * 8 + k] + red[(1 * 8 + tx2) * 8 + k]
                + red[(2 * 8 + tx2) * 8 + k] + red[(3 * 8 + tx2) * 8 + k];
        int col = tx2 * 4 + (k & 3);
        atomicAdd(&st[(k < 4 ? 0 : 32) + col], v);
    }
}

// ---------------------------------------------------------------------------
// K3: KPInv conv, role-switching layout (unchanged; measured 65.5 us).
// ---------------------------------------------------------------------------
__global__ __launch_bounds__(256, 4) void k3_kpinv(
    const float* __restrict__ y1, const float* __restrict__ st,
    const float* __restrict__ q_pts, const float* __restrict__ s_pts,
    const int* __restrict__ idx, const float* __restrict__ kp,
    const float* __restrict__ g_u1, const float* __restrict__ b_u1,
    const float* __restrict__ w_g1, const float* __restrict__ b_g1,
    const float* __restrict__ w_g2, const float* __restrict__ b_g2,
    float* __restrict__ x2, int M)
{
    __shared__ __align__(16) float a1s[32], b1s[32];
    __shared__ __align__(16) float wg1[32 * 8];
    __shared__ __align__(16) float bg1[8];
    __shared__ __align__(16) float wg2[8 * 30];
    __shared__ __align__(16) float bg2[32];
    __shared__ __align__(16) float kps[KP * 3 + 1];
    __shared__ __align__(16) float vbuf[4][2][32 * 32];
    __shared__ __align__(16) float aux[4][2][144];

    int t = threadIdx.x;
    if (t < 32) {
        float mean = st[t] * (1.0f / M);
        float var  = st[32 + t] * (1.0f / M) - mean * mean;
        float inv  = rsqrtf(var + EPS);
        float a = g_u1[t] * inv;
        a1s[t] = a;
        b1s[t] = b_u1[t] - mean * a;
    }
    wg1[t & 255] = w_g1[t & 255];
    if (t < 8)   bg1[t] = b_g1[t];
    if (t < 240) wg2[t] = w_g2[t];
    if (t < 30)  bg2[t] = b_g2[t];
    else if (t < 32) bg2[t] = 0.f;
    if (t < KP * 3) kps[t] = kp[t];
    __syncthreads();

    int wave = t >> 6, lane = t & 63;
    int p = lane >> 5;
    int q = lane & 31;
    int m = blockIdx.x * 8 + wave * 2 + p;
    bool valid = (m < M);
    int mm = valid ? m : 0;
    float* vb = &vbuf[wave][p][0];
    float* ax = &aux[wave][p][0];

    // ---------------- Phase 1: q = h ----------------
    int h = q;
    int n = idx[(size_t)mm * HNB + h];
    float qx = q_pts[mm * 3 + 0], qy = q_pts[mm * 3 + 1], qz = q_pts[mm * 3 + 2];
    float dx = s_pts[n * 3 + 0] - qx;
    float dy = s_pts[n * 3 + 1] - qy;
    float dz = s_pts[n * 3 + 2] - qz;

    float infl[KP];
#pragma unroll
    for (int k = 0; k < KP; ++k) {
        float ex = dx - kps[k * 3 + 0];
        float ey = dy - kps[k * 3 + 1];
        float ez = dz - kps[k * 3 + 2];
        float d = sqrtf(ex * ex + ey * ey + ez * ez);
        infl[k] = fmaxf(1.0f - d, 0.f);
    }

    {
        const float4* row = (const float4*)(y1 + (size_t)n * CMID);
        int hq4 = h >> 2, h3 = h & 3;
#pragma unroll
        for (int jj = 0; jj < 8; ++jj) {
            float4 f = row[jj];
            float vv[4] = {f.x, f.y, f.z, f.w};
#pragma unroll
            for (int e = 0; e < 4; ++e) {
                int c = jj * 4 + e;
                float x = vv[e] * a1s[c] + b1s[c];
                x = fmaxf(x, NEG * x);
                vb[(c << 5) + ((hq4 ^ (c & 7)) << 2) + h3] = x;
            }
        }
    }
    __builtin_amdgcn_wave_barrier();

    // ---------------- Phase 2: q = c ----------------
    {
        int c = q;
        int c7 = c & 7;
        const float* vrow = vb + (c << 5);
        float cm = -1e30f;
#pragma unroll
        for (int j = 0; j < 8; ++j) {
            const float4 f = *(const float4*)(vrow + ((j ^ c7) << 2));
            cm = fmaxf(fmaxf(fmaxf(cm, f.x), fmaxf(f.y, f.z)), f.w);
        }
        ax[c] = cm;
        __builtin_amdgcn_wave_barrier();

        int jm = c & 7;
        float acc = bg1[jm];
#pragma unroll
        for (int cc = 0; cc < 8; ++cc) {
            const float4 ce = *(const float4*)(ax + (cc << 2));
            acc += ce.x * wg1[(cc * 4 + 0) * 8 + jm];
            acc += ce.y * wg1[(cc * 4 + 1) * 8 + jm];
            acc += ce.z * wg1[(cc * 4 + 2) * 8 + jm];
            acc += ce.w * wg1[(cc * 4 + 3) * 8 + jm];
        }
        float h1v = fmaxf(acc, NEG * acc);
        if (c < 8) ax[32 + c] = h1v;
        __builtin_amdgcn_wave_barrier();

        float wv = 0.f;
        if (c < 30) {
            const float4 ha = *(const float4*)(ax + 32);
            const float4 hb = *(const float4*)(ax + 36);
            wv = bg2[c]
               + ha.x * wg2[0 * 30 + c] + ha.y * wg2[1 * 30 + c]
               + ha.z * wg2[2 * 30 + c] + ha.w * wg2[3 * 30 + c]
               + hb.x * wg2[4 * 30 + c] + hb.y * wg2[5 * 30 + c]
               + hb.z * wg2[6 * 30 + c] + hb.w * wg2[7 * 30 + c];
        }
        ax[40 + c] = wv;
    }
    __builtin_amdgcn_wave_barrier();

    // ---------------- Phase 3: q = h ----------------
    {
        float wf[32];
#pragma unroll
        for (int j = 0; j < 8; ++j) {
            const float4 wc = *(const float4*)(ax + 40 + (j << 2));
            wf[j * 4 + 0] = wc.x; wf[j * 4 + 1] = wc.y;
            wf[j * 4 + 2] = wc.z; wf[j * 4 + 3] = wc.w;
        }
        float s0 = 0.f, s1 = 0.f;
#pragma unroll
        for (int k = 0; k < KP; ++k) {
            s0 += infl[k] * wf[2 * k + 0];
            s1 += infl[k] * wf[2 * k + 1];
        }
        ax[72 + q]  = s0;
        ax[104 + q] = s1;
    }
    __builtin_amdgcn_wave_barrier();

    // ---------------- Phase 4: q = c ----------------
    {
        int c = q;
        int c7 = c & 7;
        const float* sbuf = ax + 72 + ((c >> 4) << 5);
        const float* vrow = vb + (c << 5);
        float o = 0.f;
#pragma unroll
        for (int j = 0; j < 8; ++j) {
            const float4 vv = *(const float4*)(vrow + ((j ^ c7) << 2));
            const float4 ss = *(const float4*)(sbuf + (j << 2));
            o += vv.x * ss.x + vv.y * ss.y + vv.z * ss.z + vv.w * ss.w;
        }
        if (valid) x2[(size_t)m * CMID + c] = o;
    }
}

// ---------------------------------------------------------------------------
// K4: per-channel sum/sumsq over x2 (32 channels) -> st[64:96), st[96:128)
// ---------------------------------------------------------------------------
__global__ __launch_bounds__(256) void k4_stats32(
    const float* __restrict__ x2, float* __restrict__ st, int M)
{
    int t = threadIdx.x;
    int c = t & 31;
    float sum = 0.f, sq = 0.f;
    for (int r = blockIdx.x * 8 + (t >> 5); r < M; r += gridDim.x * 8) {
        float v = x2[(size_t)r * CMID + c];
        sum += v; sq += v * v;
    }
    __shared__ float red[256];
    red[t] = sum; __syncthreads();
    if (t < 32) { float s = 0.f; for (int i = 0; i < 8; ++i) s += red[t + 32 * i]; atomicAdd(&st[64 + t], s); }
    __syncthreads();
    red[t] = sq; __syncthreads();
    if (t < 32) { float s = 0.f; for (int i = 0; i < 8; ++i) s += red[t + 32 * i]; atomicAdd(&st[96 + t], s); }
}

// ---------------------------------------------------------------------------
// K6: z = lrelu(bn_c(x2)) @ w_u2, stats only -> st[128:256), st[256:384).
// Register-tiled: block = 128 rows x 32 cols (gridDim.y = 4 col-blocks).
// S staged transposed+activated (S_T[j][row]); 2 b128 DS per 16 FMA.
// ---------------------------------------------------------------------------
__global__ __launch_bounds__(256) void k6_zstats(
    const float* __restrict__ x2, const float* __restrict__ w_u2,
    const float* __restrict__ g_c, const float* __restrict__ b_c,
    float* __restrict__ st, int M)
{
    __shared__ __align__(16) float ST[32 * 128];   // [j][row] 16 KB
    __shared__ __align__(16) float Ws[32 * 32];    // col slice, 4 KB
    __shared__ __align__(16) float acs[32], bcs[32];
    __shared__ __align__(16) float red[256];
    int t = threadIdx.x;
    int cb = blockIdx.y;
    int m0 = blockIdx.x * 128;
    if (t < 32) {
        float mean = st[64 + t] * (1.0f / M);
        float var  = st[96 + t] * (1.0f / M) - mean * mean;
        float inv  = rsqrtf(var + EPS);
        float a = g_c[t] * inv;
        acs[t] = a; bcs[t] = b_c[t] - mean * a;
    }
    for (int i = t; i < 32 * 32; i += 256)
        Ws[i] = w_u2[(i >> 5) * CIN + cb * 32 + (i & 31)];
    __syncthreads();

    // stage S_T
    int srow = t & 127, shh = t >> 7;
    int gr = m0 + srow;
    const float4* xp = (const float4*)(x2 + (size_t)gr * CMID + shh * 16);
    float4 f0, f1, f2, f3;
    if (gr < M) { f0 = xp[0]; f1 = xp[1]; f2 = xp[2]; f3 = xp[3]; }
    else { f0 = f1 = f2 = f3 = make_float4(0.f, 0.f, 0.f, 0.f); }
    {
        float vv[16] = {f0.x, f0.y, f0.z, f0.w, f1.x, f1.y, f1.z, f1.w,
                        f2.x, f2.y, f2.z, f2.w, f3.x, f3.y, f3.z, f3.w};
        int cbse = shh * 16;
#pragma unroll
        for (int e = 0; e < 16; ++e) {
            int c = cbse + e;
            float x = vv[e] * acs[c] + bcs[c];
            x = fmaxf(x, NEG * x);
            ST[c * 128 + srow] = (gr < M) ? x : 0.f;
        }
    }
    __syncthreads();

    int tx = t & 7, ty = t >> 3;
    float acc[4][4] = {{0.f}};
#pragma unroll
    for (int j = 0; j < 32; ++j) {
        float4 av = *(const float4*)(ST + j * 128 + ty * 4);
        float4 bv = *(const float4*)(Ws + j * 32 + tx * 4);
        acc[0][0] += av.x * bv.x; acc[0][1] += av.x * bv.y; acc[0][2] += av.x * bv.z; acc[0][3] += av.x * bv.w;
        acc[1][0] += av.y * bv.x; acc[1][1] += av.y * bv.y; acc[1][2] += av.y * bv.z; acc[1][3] += av.y * bv.w;
        acc[2][0] += av.z * bv.x; acc[2][1] += av.z * bv.y; acc[2][2] += av.z * bv.z; acc[2][3] += av.z * bv.w;
        acc[3][0] += av.w * bv.x; acc[3][1] += av.w * bv.y; acc[3][2] += av.w * bv.z; acc[3][3] += av.w * bv.w;
    }
    // stats of z (pad rows contribute 0)
    float s4[4], q4[4];
#pragma unroll
    for (int e = 0; e < 4; ++e) {
        s4[e] = acc[0][e] + acc[1][e] + acc[2][e] + acc[3][e];
        q4[e] = acc[0][e] * acc[0][e] + acc[1][e] * acc[1][e]
              + acc[2][e] * acc[2][e] + acc[3][e] * acc[3][e];
    }
#pragma unroll
    for (int off = 8; off <= 32; off <<= 1) {
#pragma unroll
        for (int e = 0; e < 4; ++e) {
            s4[e] += __shfl_xor(s4[e], off);
            q4[e] += __shfl_xor(q4[e], off);
        }
    }
    int lw = t >> 6, ll = t & 63;
    if (ll < 8) {
#pragma unroll
        for (int e = 0; e < 4; ++e) {
            red[(lw * 8 + ll) * 8 + e] = s4[e];
            red[(lw * 8 + ll) * 8 + 4 + e] = q4[e];
        }
    }
    __syncthreads();
    if (t < 64) {
        int tx2 = t >> 3, k = t & 7;
        float v = red[(0 * 8 + tx2) * 8 + k] + red[(1 * 8 + tx2) * 8 + k]
                + red[(2 * 8 + tx2) * 8 + k] + red[(3 * 8 + tx2) * 8 + k];
        int col = cb * 32 + tx2 * 4 + (k & 3);
        atomicAdd(&st[(k < 4 ? 128 : 256) + col], v);
    }
}

// ---------------------------------------------------------------------------
// K8: recompute z (same tiling as K6), apply bn_u2, residual, lrelu -> out.
// ---------------------------------------------------------------------------
__global__ __launch_bounds__(256) void k8_final(
    const float* __restrict__ x2, const float* __restrict__ w_u2,
    const float* __restrict__ g_c, const float* __restrict__ b_c,
    const float* __restrict__ g_u2, const float* __restrict__ b_u2,
    const float* __restrict__ s_feats, const float* __restrict__ st,
    float* __restrict__ out, int M)
{
    __shared__ __align__(16) float ST[32 * 128];
    __shared__ __align__(16) float Ws[32 * 32];
    __shared__ __align__(16) float acs[32], bcs[32];
    __shared__ __align__(16) float a2s[32], b2s[32];
    int t = threadIdx.x;
    int cb = blockIdx.y;
    int m0 = blockIdx.x * 128;
    if (t < 32) {
        float mean = st[64 + t] * (1.0f / M);
        float var  = st[96 + t] * (1.0f / M) - mean * mean;
        float inv  = rsqrtf(var + EPS);
        float a = g_c[t] * inv;
        acs[t] = a; bcs[t] = b_c[t] - mean * a;
        int c = cb * 32 + t;
        float mean2 = st[128 + c] * (1.0f / M);
        float var2  = st[256 + c] * (1.0f / M) - mean2 * mean2;
        float inv2  = rsqrtf(var2 + EPS);
        float a2 = g_u2[c] * inv2;
        a2s[t] = a2; b2s[t] = b_u2[c] - mean2 * a2;
    }
    for (int i = t; i < 32 * 32; i += 256)
        Ws[i] = w_u2[(i >> 5) * CIN + cb * 32 + (i & 31)];
    __syncthreads();

    int srow = t & 127, shh = t >> 7;
    int gr = m0 + srow;
    const float4* xp = (const float4*)(x2 + (size_t)gr * CMID + shh * 16);
    float4 f0, f1, f2, f3;
    if (gr < M) { f0 = xp[0]; f1 = xp[1]; f2 = xp[2]; f3 = xp[3]; }
    else { f0 = f1 = f2 = f3 = make_float4(0.f, 0.f, 0.f, 0.f); }
    {
        float vv[16] = {f0.x, f0.y, f0.z, f0.w, f1.x, f1.y, f1.z, f1.w,
                        f2.x, f2.y, f2.z, f2.w, f3.x, f3.y, f3.z, f3.w};
        int cbse = shh * 16;
#pragma unroll
        for (int e = 0; e < 16; ++e) {
            int c = cbse + e;
            float x = vv[e] * acs[c] + bcs[c];
            x = fmaxf(x, NEG * x);
            ST[c * 128 + srow] = (gr < M) ? x : 0.f;
        }
    }
    __syncthreads();

    int tx = t & 7, ty = t >> 3;
    float acc[4][4] = {{0.f}};
#pragma unroll
    for (int j = 0; j < 32; ++j) {
        float4 av = *(const float4*)(ST + j * 128 + ty * 4);
        float4 bv = *(const float4*)(Ws + j * 32 + tx * 4);
        acc[0][0] += av.x * bv.x; acc[0][1] += av.x * bv.y; acc[0][2] += av.x * bv.z; acc[0][3] += av.x * bv.w;
        acc[1][0] += av.y * bv.x; acc[1][1] += av.y * bv.y; acc[1][2] += av.y * bv.z; acc[1][3] += av.y * bv.w;
        acc[2][0] += av.z * bv.x; acc[2][1] += av.z * bv.y; acc[2][2] += av.z * bv.z; acc[2][3] += av.z * bv.w;
        acc[3][0] += av.w * bv.x; acc[3][1] += av.w * bv.y; acc[3][2] += av.w * bv.z; acc[3][3] += av.w * bv.w;
    }
    int lc = tx * 4;
    float a0 = a2s[lc + 0], a1 = a2s[lc + 1], a2v = a2s[lc + 2], a3 = a2s[lc + 3];
    float bb0 = b2s[lc + 0], bb1 = b2s[lc + 1], bb2 = b2s[lc + 2], bb3 = b2s[lc + 3];
#pragma unroll
    for (int i = 0; i < 4; ++i) {
        int r = m0 + ty * 4 + i;
        if (r < M) {
            size_t gi = (size_t)r * CIN + cb * 32 + lc;
            float4 sf = *(const float4*)(s_feats + gi);
            float v0 = acc[i][0] * a0 + bb0 + sf.x;
            float v1 = acc[i][1] * a1 + bb1 + sf.y;
            float v2 = acc[i][2] * a2v + bb2 + sf.z;
            float v3 = acc[i][3] * a3 + bb3 + sf.w;
            v0 = fmaxf(v0, NEG * v0); v1 = fmaxf(v1, NEG * v1);
            v2 = fmaxf(v2, NEG * v2); v3 = fmaxf(v3, NEG * v3);
            *(float4*)(out + gi) = make_float4(v0, v1, v2, v3);
        }
    }
}

extern "C" void kernel_launch(void* const* d_in, const int* in_sizes, int n_in,
                              void* d_out, int out_size, void* d_ws, size_t ws_size,
                              hipStream_t stream) {
    const float* q_pts   = (const float*)d_in[0];
    const float* s_pts   = (const float*)d_in[1];
    const float* s_feats = (const float*)d_in[2];
    const int*   idx     = (const int*)d_in[3];
    const float* kp      = (const float*)d_in[4];
    const float* w_u1    = (const float*)d_in[5];
    const float* g_u1    = (const float*)d_in[6];
    const float* b_u1    = (const float*)d_in[7];
    const float* w_g1    = (const float*)d_in[8];
    const float* b_g1    = (const float*)d_in[9];
    const float* w_g2    = (const float*)d_in[10];
    const float* b_g2    = (const float*)d_in[11];
    const float* g_c     = (const float*)d_in[12];
    const float* b_c     = (const float*)d_in[13];
    const float* w_u2    = (const float*)d_in[14];
    const float* g_u2    = (const float*)d_in[15];
    const float* b_u2    = (const float*)d_in[16];

    int M = in_sizes[3] / HNB;   // 50000

    float* ws = (float*)d_ws;
    float* y1 = ws;                       // M*32
    float* x2 = ws + (size_t)M * CMID;    // M*32
    float* st = ws + (size_t)M * 2 * CMID; // 384 floats of stats

    hipMemsetAsync(st, 0, 384 * sizeof(float), stream);

    int nbr = (M + 127) / 128;   // 128-row blocks
    k1_gemm1<<<nbr, 256, 0, stream>>>(s_feats, w_u1, y1, st, M);
    k3_kpinv<<<(M + 7) / 8, 256, 0, stream>>>(y1, st, q_pts, s_pts, idx, kp,
                                              g_u1, b_u1, w_g1, b_g1, w_g2, b_g2,
                                              x2, M);
    k4_stats32<<<128, 256, 0, stream>>>(x2, st, M);
    k6_zstats<<<dim3(nbr, 4), 256, 0, stream>>>(x2, w_u2, g_c, b_c, st, M);
    k8_final<<<dim3(nbr, 4), 256, 0, stream>>>(x2, w_u2, g_c, b_c, g_u2, b_u2,
                                               s_feats, st, (float*)d_out, M);
}